// Round 1
// baseline (807.542 us; speedup 1.0000x reference)
//
#include <hip/hip_runtime.h>

// Problem: y[b,s,o] = sum_i x[b,s,i] * (W[o,i] + dW[o,i]) + bias[o]
//   W[o,i] = (q[o,i] - z[g]) * s[g],  g = (o*4096+i)/128  (int4, 2/byte, byte stored as int32)
// M=8192 (=4*2048), N=4096 (OUT), K=4096 (IN)
//
// Strategy: fp16 hi/lo split GEMM (3 MFMA terms: xh*wh + xh*wl + xl*wh) on
// mfma_f32_16x16x32_f16. Max error ~1e-5 relative vs fp32 reference.

#define M_DIM 8192
#define N_DIM 4096
#define K_DIM 4096
#define NUMEL (N_DIM * K_DIM)

typedef _Float16 half_t;
typedef __attribute__((ext_vector_type(4))) _Float16 half4v;
typedef __attribute__((ext_vector_type(8))) _Float16 half8v;
typedef __attribute__((ext_vector_type(4))) float float4v;
typedef __attribute__((ext_vector_type(4))) int int4v;

#define BM 128
#define BN 128
#define BK 64
// padded LDS row stride in halves: 144B/row -> bank offset 4*row mod 32 ->
// only 2-way aliasing on ds_read_b128 fragment reads (free per m136)
#define LDT 72

// ---------- Phase 1a: dequant + delta -> fp16 hi/lo split of W_eff ----------
__global__ __launch_bounds__(256) void k_dequant_split(
    const int* __restrict__ qp, const float* __restrict__ sc,
    const float* __restrict__ zr, const float* __restrict__ dwt,
    half_t* __restrict__ Wh, half_t* __restrict__ Wl)
{
    const long t = (long)blockIdx.x * 256 + threadIdx.x;
    const long flat = t * 8;                 // 8 weights per thread, one group
    const int g = (int)(flat >> 7);
    const float s = sc[g];
    const float zs = zr[g] * s;
    int4v q4 = *(const int4v*)(qp + (flat >> 1));
    float4v d0 = *(const float4v*)(dwt + flat);
    float4v d1 = *(const float4v*)(dwt + flat + 4);
    float d[8] = {d0[0], d0[1], d0[2], d0[3], d1[0], d1[1], d1[2], d1[3]};
    float w[8];
#pragma unroll
    for (int j = 0; j < 4; ++j) {
        w[2*j]   = fmaf((float)(q4[j] & 15),        s, d[2*j]   - zs);
        w[2*j+1] = fmaf((float)((q4[j] >> 4) & 15), s, d[2*j+1] - zs);
    }
    half8v vh, vl;
#pragma unroll
    for (int e = 0; e < 8; ++e) {
        half_t h = (half_t)w[e];
        vh[e] = h;
        vl[e] = (half_t)(w[e] - (float)h);
    }
    *(half8v*)(Wh + flat) = vh;
    *(half8v*)(Wl + flat) = vl;
}

// ---------- Phase 1b: split x (fp32) -> fp16 hi/lo ----------
__global__ __launch_bounds__(256) void k_split_x(
    const float* __restrict__ X, half_t* __restrict__ Xh, half_t* __restrict__ Xl)
{
    const long flat = ((long)blockIdx.x * 256 + threadIdx.x) * 8;
    float4v x0 = *(const float4v*)(X + flat);
    float4v x1 = *(const float4v*)(X + flat + 4);
    float xv[8] = {x0[0], x0[1], x0[2], x0[3], x1[0], x1[1], x1[2], x1[3]};
    half8v vh, vl;
#pragma unroll
    for (int e = 0; e < 8; ++e) {
        half_t h = (half_t)xv[e];
        vh[e] = h;
        vl[e] = (half_t)(xv[e] - (float)h);
    }
    *(half8v*)(Xh + flat) = vh;
    *(half8v*)(Xl + flat) = vl;
}

// ---------- Phase 2: 3-term split GEMM ----------
// FUSED=1: no workspace; convert x and dequant W during LDS staging.
template<int FUSED>
__global__ __launch_bounds__(256, 2) void k_gemm3(
    const float* __restrict__ X,
    const half_t* __restrict__ Xh, const half_t* __restrict__ Xl,
    const half_t* __restrict__ Wh, const half_t* __restrict__ Wl,
    const int* __restrict__ qp, const float* __restrict__ sc,
    const float* __restrict__ zr, const float* __restrict__ dwt,
    const float* __restrict__ bias, float* __restrict__ Y)
{
    __shared__ __align__(16) half_t Ah[BM * LDT];
    __shared__ __align__(16) half_t Al[BM * LDT];
    __shared__ __align__(16) half_t Bh[BN * LDT];
    __shared__ __align__(16) half_t Bl[BN * LDT];

    const int tid  = threadIdx.x;
    const int lane = tid & 63;
    const int wave = tid >> 6;
    const int wm = wave >> 1, wn = wave & 1;     // 2x2 waves, 64x64 each
    const int bn = blockIdx.x & 31;              // N_DIM/BN == 32
    const int bm = blockIdx.x >> 5;
    const long m0 = (long)bm * BM;
    const long n0 = (long)bn * BN;

    const float4v zero4 = {0.f, 0.f, 0.f, 0.f};
    float4v acc[4][4];
#pragma unroll
    for (int i = 0; i < 4; ++i)
#pragma unroll
        for (int j = 0; j < 4; ++j) acc[i][j] = zero4;

    const int fr = lane & 15;          // fragment row
    const int ko = (lane >> 4) * 8;    // k offset within a 32-wide k-sub

    for (int k0 = 0; k0 < K_DIM; k0 += BK) {
        // ---- stage A (x hi/lo) ----
        if constexpr (FUSED) {
            const int ar = tid >> 4;
            const int ac = (tid & 15) * 4;
#pragma unroll
            for (int rr = 0; rr < 8; ++rr) {
                const int row = ar + rr * 16;
                float4v xv = *(const float4v*)(X + (m0 + row) * K_DIM + k0 + ac);
                half4v h, l;
#pragma unroll
                for (int j = 0; j < 4; ++j) {
                    half_t hh = (half_t)xv[j];
                    h[j] = hh;
                    l[j] = (half_t)(xv[j] - (float)hh);
                }
                *(half4v*)(Ah + row * LDT + ac) = h;
                *(half4v*)(Al + row * LDT + ac) = l;
            }
        } else {
            const int cr = tid >> 3;
            const int cc = (tid & 7) * 8;
#pragma unroll
            for (int rr = 0; rr < 4; ++rr) {
                const int row = cr + rr * 32;
                *(half8v*)(Ah + row * LDT + cc) =
                    *(const half8v*)(Xh + (m0 + row) * K_DIM + k0 + cc);
                *(half8v*)(Al + row * LDT + cc) =
                    *(const half8v*)(Xl + (m0 + row) * K_DIM + k0 + cc);
            }
        }
        // ---- stage B (W_eff hi/lo, B^T layout: row n holds K-contig) ----
        {
            const int cr = tid >> 3;
            const int cc = (tid & 7) * 8;
            if constexpr (FUSED) {
#pragma unroll
                for (int rr = 0; rr < 4; ++rr) {
                    const int row = cr + rr * 32;
                    const long n = n0 + row;
                    const int g = (int)(n * 32 + (k0 >> 7));
                    const float s = sc[g];
                    const float zs = zr[g] * s;
                    const long flat = n * K_DIM + k0 + cc;
                    int4v q4 = *(const int4v*)(qp + (flat >> 1));
                    float4v d0 = *(const float4v*)(dwt + flat);
                    float4v d1 = *(const float4v*)(dwt + flat + 4);
                    float d[8] = {d0[0], d0[1], d0[2], d0[3], d1[0], d1[1], d1[2], d1[3]};
                    half8v vh, vl;
#pragma unroll
                    for (int j = 0; j < 4; ++j) {
                        float w0 = fmaf((float)(q4[j] & 15),        s, d[2*j]   - zs);
                        float w1 = fmaf((float)((q4[j] >> 4) & 15), s, d[2*j+1] - zs);
                        half_t h0 = (half_t)w0, h1 = (half_t)w1;
                        vh[2*j]   = h0; vl[2*j]   = (half_t)(w0 - (float)h0);
                        vh[2*j+1] = h1; vl[2*j+1] = (half_t)(w1 - (float)h1);
                    }
                    *(half8v*)(Bh + row * LDT + cc) = vh;
                    *(half8v*)(Bl + row * LDT + cc) = vl;
                }
            } else {
#pragma unroll
                for (int rr = 0; rr < 4; ++rr) {
                    const int row = cr + rr * 32;
                    *(half8v*)(Bh + row * LDT + cc) =
                        *(const half8v*)(Wh + (n0 + row) * K_DIM + k0 + cc);
                    *(half8v*)(Bl + row * LDT + cc) =
                        *(const half8v*)(Wl + (n0 + row) * K_DIM + k0 + cc);
                }
            }
        }
        __syncthreads();

        // ---- compute: acc += xh*wh + xh*wl + xl*wh ----
#pragma unroll
        for (int ks = 0; ks < 2; ++ks) {
            const int kk = ks * 32 + ko;
            half8v ah[4], al[4], bh[4], bl[4];
#pragma unroll
            for (int i = 0; i < 4; ++i) {
                ah[i] = *(const half8v*)(Ah + (wm * 64 + i * 16 + fr) * LDT + kk);
                al[i] = *(const half8v*)(Al + (wm * 64 + i * 16 + fr) * LDT + kk);
                bh[i] = *(const half8v*)(Bh + (wn * 64 + i * 16 + fr) * LDT + kk);
                bl[i] = *(const half8v*)(Bl + (wn * 64 + i * 16 + fr) * LDT + kk);
            }
#pragma unroll
            for (int i = 0; i < 4; ++i)
#pragma unroll
                for (int j = 0; j < 4; ++j) {
                    acc[i][j] = __builtin_amdgcn_mfma_f32_16x16x32_f16(ah[i], bh[j], acc[i][j], 0, 0, 0);
                    acc[i][j] = __builtin_amdgcn_mfma_f32_16x16x32_f16(ah[i], bl[j], acc[i][j], 0, 0, 0);
                    acc[i][j] = __builtin_amdgcn_mfma_f32_16x16x32_f16(al[i], bh[j], acc[i][j], 0, 0, 0);
                }
        }
        __syncthreads();
    }

    // ---- epilogue: C/D layout col=lane&15, row=(lane>>4)*4+reg ----
#pragma unroll
    for (int i = 0; i < 4; ++i) {
        const long mrow = m0 + wm * 64 + i * 16 + (lane >> 4) * 4;
#pragma unroll
        for (int j = 0; j < 4; ++j) {
            const long col = n0 + wn * 64 + j * 16 + (lane & 15);
            const float b = bias[col];
#pragma unroll
            for (int r = 0; r < 4; ++r) {
                Y[(mrow + r) * N_DIM + col] = acc[i][j][r] + b;
            }
        }
    }
}

extern "C" void kernel_launch(void* const* d_in, const int* in_sizes, int n_in,
                              void* d_out, int out_size, void* d_ws, size_t ws_size,
                              hipStream_t stream)
{
    const float* X  = (const float*)d_in[0];
    const int*   qp = (const int*)d_in[1];
    const float* sc = (const float*)d_in[2];
    const float* zr = (const float*)d_in[3];
    const float* dwt = (const float*)d_in[4];
    const float* bs = (const float*)d_in[5];
    float* Y = (float*)d_out;

    const size_t NK = (size_t)N_DIM * K_DIM;   // 16,777,216
    const size_t MK = (size_t)M_DIM * K_DIM;   // 33,554,432
    const size_t need = (NK * 2 + MK * 2) * sizeof(half_t);  // 201,326,592 B

    dim3 blk(256);
    dim3 ggrid((M_DIM / BM) * (N_DIM / BN));   // 64 * 32 = 2048 blocks

    if (ws_size >= need) {
        half_t* Wh = (half_t*)d_ws;
        half_t* Wl = Wh + NK;
        half_t* Xh = Wl + NK;
        half_t* Xl = Xh + MK;
        k_dequant_split<<<dim3(NUMEL / 8 / 256), blk, 0, stream>>>(qp, sc, zr, dwt, Wh, Wl);
        k_split_x<<<dim3(MK / 8 / 256), blk, 0, stream>>>(X, Xh, Xl);
        k_gemm3<0><<<ggrid, blk, 0, stream>>>(X, Xh, Xl, Wh, Wl, qp, sc, zr, dwt, bs, Y);
    } else {
        k_gemm3<1><<<ggrid, blk, 0, stream>>>(X, nullptr, nullptr, nullptr, nullptr,
                                              qp, sc, zr, dwt, bs, Y);
    }
}

// Round 2
// 315.123 us; speedup vs baseline: 2.5626x; 2.5626x over previous
//
#include <hip/hip_runtime.h>

// y[m,o] = sum_k x[m,k] * (W[o,k] + dW[o,k]) + bias[o],  W int4-dequant.
// M=8192, N=4096(OUT), K=4096(IN).
//
// Strategy: single-term fp16 GEMM on mfma_f32_16x16x32_f16.
//   Phase 1: dequant W(+dW) -> fp16, convert x -> fp16; both written
//            TILE-PACKED (128x64 f16 = 16KB contiguous) and PRE-XOR-SWIZZLED
//            (byte ^= (row&7)<<4) so the GEMM can stage with linear
//            global_load_lds and read fragments conflict-free.
//   Phase 2: 128x128 tile GEMM, BK=64, 4 waves (2x2 of 64x64),
//            global_load_lds staging, swizzled ds_read_b128 fragments.
// Error budget: fp16 rounding of x and W -> max err ~1.5e-2, invisible vs
// the 0.125 reference-side noise measured with the near-exact 3-term split.

#define M_DIM 8192
#define N_DIM 4096
#define K_DIM 4096
#define NUMEL (N_DIM * K_DIM)

typedef _Float16 half_t;
typedef __attribute__((ext_vector_type(4))) _Float16 half4v;
typedef __attribute__((ext_vector_type(8))) _Float16 half8v;
typedef __attribute__((ext_vector_type(4))) float float4v;
typedef __attribute__((ext_vector_type(4))) int int4v;

#define BM 128
#define BN 128
#define BK 64
#define KTILES (K_DIM / BK)      // 64 k-tiles per panel
#define TILE_BYTES 16384         // 128 rows x 64 cols x 2B
#define LDT 72                   // padded row stride (halves) for fused fallback

static __device__ __forceinline__ void gload16(const void* g, void* l) {
    __builtin_amdgcn_global_load_lds(
        (const __attribute__((address_space(1))) void*)g,
        (__attribute__((address_space(3))) void*)l, 16, 0, 0);
}

// ---------- Phase 1a: dequant+delta -> fp16, tile-packed + swizzled ----------
__global__ __launch_bounds__(256) void k_pack_w(
    const int* __restrict__ qp, const float* __restrict__ sc,
    const float* __restrict__ zr, const float* __restrict__ dwt,
    unsigned char* __restrict__ Wp)
{
    const long t = (long)blockIdx.x * 256 + threadIdx.x;
    const long flat = t * 8;                  // 8 weights (16B of fp16), one group
    const int g = (int)(flat >> 7);
    const float s = sc[g];
    const float zs = zr[g] * s;
    int4v q4 = *(const int4v*)(qp + (flat >> 1));
    float4v d0 = *(const float4v*)(dwt + flat);
    float4v d1 = *(const float4v*)(dwt + flat + 4);
    float d[8] = {d0[0], d0[1], d0[2], d0[3], d1[0], d1[1], d1[2], d1[3]};
    half8v vh;
#pragma unroll
    for (int j = 0; j < 4; ++j) {
        vh[2*j]   = (half_t)fmaf((float)(q4[j] & 15),        s, d[2*j]   - zs);
        vh[2*j+1] = (half_t)fmaf((float)((q4[j] >> 4) & 15), s, d[2*j+1] - zs);
    }
    const int n = (int)(flat >> 12);          // output row (K=4096 per row)
    const int k = (int)(flat & 4095);
    const int row = n & 127;                  // row within tile
    const int a = (row << 7) + ((k & 63) << 1);
    const int b = a ^ ((row & 7) << 4);       // pre-swizzle (involution)
    *(half8v*)(Wp + (((size_t)((n >> 7) * KTILES + (k >> 6))) << 14) + b) = vh;
}

// ---------- Phase 1b: x fp32 -> fp16, tile-packed + swizzled ----------
__global__ __launch_bounds__(256) void k_pack_x(
    const float* __restrict__ X, unsigned char* __restrict__ Xp)
{
    const long flat = ((long)blockIdx.x * 256 + threadIdx.x) * 8;
    float4v x0 = *(const float4v*)(X + flat);
    float4v x1 = *(const float4v*)(X + flat + 4);
    half8v vh;
    vh[0] = (half_t)x0[0]; vh[1] = (half_t)x0[1];
    vh[2] = (half_t)x0[2]; vh[3] = (half_t)x0[3];
    vh[4] = (half_t)x1[0]; vh[5] = (half_t)x1[1];
    vh[6] = (half_t)x1[2]; vh[7] = (half_t)x1[3];
    const int m = (int)(flat >> 12);
    const int k = (int)(flat & 4095);
    const int row = m & 127;
    const int a = (row << 7) + ((k & 63) << 1);
    const int b = a ^ ((row & 7) << 4);
    *(half8v*)(Xp + (((size_t)((m >> 7) * KTILES + (k >> 6))) << 14) + b) = vh;
}

// ---------- Phase 2: fp16 GEMM ----------
// PACKED=1: stage from pre-packed swizzled tiles via global_load_lds.
// PACKED=0: fallback (no workspace): convert/dequant during reg staging.
template<int PACKED>
__global__ __launch_bounds__(256, 4) void k_gemm1(
    const unsigned char* __restrict__ Ap, const unsigned char* __restrict__ Bp,
    const float* __restrict__ X, const int* __restrict__ qp,
    const float* __restrict__ sc, const float* __restrict__ zr,
    const float* __restrict__ dwt,
    const float* __restrict__ bias, float* __restrict__ Y)
{
    __shared__ __align__(16) unsigned char smem[36864];

    const int tid  = threadIdx.x;
    const int lane = tid & 63;
    const int wave = tid >> 6;
    const int wm = wave >> 1, wn = wave & 1;     // 2x2 waves, 64x64 each
    const int bn = blockIdx.x & 31;              // N_DIM/BN == 32
    const int bm = blockIdx.x >> 5;
    const long m0 = (long)bm * BM;
    const long n0 = (long)bn * BN;
    const int fr = lane & 15;

    const float4v zero4 = {0.f, 0.f, 0.f, 0.f};
    float4v acc[4][4];
#pragma unroll
    for (int i = 0; i < 4; ++i)
#pragma unroll
        for (int j = 0; j < 4; ++j) acc[i][j] = zero4;

    if constexpr (PACKED) {
        unsigned char* Ab = smem;
        unsigned char* Bb = smem + TILE_BYTES;
        const int kg16 = (lane >> 4) << 4;       // 16B k-group offset
        const unsigned char* at0 = Ap + (((size_t)bm * KTILES) << 14)
                                 + (wave << 12) + (lane << 4);
        const unsigned char* bt0 = Bp + (((size_t)bn * KTILES) << 14)
                                 + (wave << 12) + (lane << 4);
        for (int kb = 0; kb < KTILES; ++kb) {
            const unsigned char* at = at0 + ((size_t)kb << 14);
            const unsigned char* bt = bt0 + ((size_t)kb << 14);
#pragma unroll
            for (int i = 0; i < 4; ++i) {
                gload16(at + i * 1024, Ab + (wave << 12) + i * 1024);
                gload16(bt + i * 1024, Bb + (wave << 12) + i * 1024);
            }
            __syncthreads();   // compiler emits vmcnt(0) drain before barrier
#pragma unroll
            for (int ks = 0; ks < 2; ++ks) {
                const int c2 = ks * 64 + kg16;
                half8v ah[4], bh[4];
#pragma unroll
                for (int i = 0; i < 4; ++i) {
                    const int ra = wm * 64 + i * 16 + fr;
                    ah[i] = *(const half8v*)(Ab + (((ra << 7) + c2) ^ ((ra & 7) << 4)));
                    const int rb = wn * 64 + i * 16 + fr;
                    bh[i] = *(const half8v*)(Bb + (((rb << 7) + c2) ^ ((rb & 7) << 4)));
                }
#pragma unroll
                for (int i = 0; i < 4; ++i)
#pragma unroll
                    for (int j = 0; j < 4; ++j)
                        acc[i][j] = __builtin_amdgcn_mfma_f32_16x16x32_f16(
                            ah[i], bh[j], acc[i][j], 0, 0, 0);
            }
            __syncthreads();
        }
    } else {
        half_t* Ah = (half_t*)smem;              // [128][LDT]
        half_t* Bh = (half_t*)(smem + 2 * BM * LDT);
        const int ko = (lane >> 4) * 8;
        for (int k0 = 0; k0 < K_DIM; k0 += BK) {
            {   // stage A: fp32 -> fp16
                const int ar = tid >> 4;
                const int ac = (tid & 15) * 4;
#pragma unroll
                for (int rr = 0; rr < 8; ++rr) {
                    const int row = ar + rr * 16;
                    float4v xv = *(const float4v*)(X + (m0 + row) * K_DIM + k0 + ac);
                    half4v h;
#pragma unroll
                    for (int j = 0; j < 4; ++j) h[j] = (half_t)xv[j];
                    *(half4v*)(Ah + row * LDT + ac) = h;
                }
            }
            {   // stage B: dequant
                const int cr = tid >> 3;
                const int cc = (tid & 7) * 8;
#pragma unroll
                for (int rr = 0; rr < 4; ++rr) {
                    const int row = cr + rr * 32;
                    const long n = n0 + row;
                    const int g = (int)(n * 32 + (k0 >> 7));
                    const float s = sc[g];
                    const float zs = zr[g] * s;
                    const long flat = n * K_DIM + k0 + cc;
                    int4v q4 = *(const int4v*)(qp + (flat >> 1));
                    float4v d0 = *(const float4v*)(dwt + flat);
                    float4v d1 = *(const float4v*)(dwt + flat + 4);
                    float d[8] = {d0[0], d0[1], d0[2], d0[3], d1[0], d1[1], d1[2], d1[3]};
                    half8v vh;
#pragma unroll
                    for (int j = 0; j < 4; ++j) {
                        vh[2*j]   = (half_t)fmaf((float)(q4[j] & 15),        s, d[2*j]   - zs);
                        vh[2*j+1] = (half_t)fmaf((float)((q4[j] >> 4) & 15), s, d[2*j+1] - zs);
                    }
                    *(half8v*)(Bh + row * LDT + cc) = vh;
                }
            }
            __syncthreads();
#pragma unroll
            for (int ks = 0; ks < 2; ++ks) {
                const int kk = ks * 32 + ko;
                half8v ah[4], bh[4];
#pragma unroll
                for (int i = 0; i < 4; ++i) {
                    ah[i] = *(const half8v*)(Ah + (wm * 64 + i * 16 + fr) * LDT + kk);
                    bh[i] = *(const half8v*)(Bh + (wn * 64 + i * 16 + fr) * LDT + kk);
                }
#pragma unroll
                for (int i = 0; i < 4; ++i)
#pragma unroll
                    for (int j = 0; j < 4; ++j)
                        acc[i][j] = __builtin_amdgcn_mfma_f32_16x16x32_f16(
                            ah[i], bh[j], acc[i][j], 0, 0, 0);
            }
            __syncthreads();
        }
    }

    // ---- epilogue: C/D layout col=lane&15, row=(lane>>4)*4+reg ----
#pragma unroll
    for (int i = 0; i < 4; ++i) {
        const long mrow = m0 + wm * 64 + i * 16 + (lane >> 4) * 4;
#pragma unroll
        for (int j = 0; j < 4; ++j) {
            const long col = n0 + wn * 64 + j * 16 + (lane & 15);
            const float b = bias[col];
#pragma unroll
            for (int r = 0; r < 4; ++r) {
                Y[(mrow + r) * N_DIM + col] = acc[i][j][r] + b;
            }
        }
    }
}

extern "C" void kernel_launch(void* const* d_in, const int* in_sizes, int n_in,
                              void* d_out, int out_size, void* d_ws, size_t ws_size,
                              hipStream_t stream)
{
    const float* X  = (const float*)d_in[0];
    const int*   qp = (const int*)d_in[1];
    const float* sc = (const float*)d_in[2];
    const float* zr = (const float*)d_in[3];
    const float* dwt = (const float*)d_in[4];
    const float* bs = (const float*)d_in[5];
    float* Y = (float*)d_out;

    const size_t needB = (size_t)N_DIM * K_DIM * 2;   // 33,554,432 B (Wh tiles)
    const size_t needA = (size_t)M_DIM * K_DIM * 2;   // 67,108,864 B (Xh tiles)

    dim3 blk(256);
    dim3 ggrid((M_DIM / BM) * (N_DIM / BN));          // 64 * 32 = 2048 blocks

    if (ws_size >= needA + needB) {
        unsigned char* Bpk = (unsigned char*)d_ws;
        unsigned char* Apk = Bpk + needB;
        k_pack_w<<<dim3(NUMEL / 8 / 256), blk, 0, stream>>>(qp, sc, zr, dwt, Bpk);
        k_pack_x<<<dim3((M_DIM * K_DIM) / 8 / 256), blk, 0, stream>>>(X, Apk);
        k_gemm1<1><<<ggrid, blk, 0, stream>>>(Apk, Bpk, nullptr, nullptr, nullptr,
                                              nullptr, nullptr, bs, Y);
    } else {
        k_gemm1<0><<<ggrid, blk, 0, stream>>>(nullptr, nullptr, X, qp, sc, zr,
                                              dwt, bs, Y);
    }
}

// Round 3
// 297.049 us; speedup vs baseline: 2.7186x; 1.0608x over previous
//
#include <hip/hip_runtime.h>

// y[m,o] = sum_k x[m,k] * (W[o,k] + dW[o,k]) + bias[o],  W int4-dequant.
// M=8192, N=4096(OUT), K=4096(IN).
//
// Round 3: 256x256-tile 8-phase GEMM (T2 swizzle + T3/T4 counted vmcnt + T5
// setprio). Pack kernels (unchanged) emit 128x64 fp16 tiles (16KB), XOR-
// swizzled (byte ^= (row&7)<<4) so staging is linear global_load_lds and
// fragment ds_read_b128 is conflict-free (validated round 2: 0 conflicts).
//
// Liveness-derived stage/wait schedule (race-free by construction):
//   K-tile phases p0..p3 read: p0: A[0-3]+B[0-1], p1: B[2-3], p2: A[4-7], p3: -
//   => A-halves of a buf die at p2's end-barrier, B-halves at p1's.
//   Stages: p0: B(t+1)->buf^1 | p3: A(t+2)->buf | p4: B(t+2)->buf | p7: A(t+3)->buf^1
//   Waits: end of p3/p7 only: vmcnt(4)  (12 outstanding, oldest 8 = needed tile)

#define M_DIM 8192
#define N_DIM 4096
#define K_DIM 4096
#define NUMEL (N_DIM * K_DIM)

typedef _Float16 half_t;
typedef __attribute__((ext_vector_type(4))) _Float16 half4v;
typedef __attribute__((ext_vector_type(8))) _Float16 half8v;
typedef __attribute__((ext_vector_type(4))) float float4v;
typedef __attribute__((ext_vector_type(4))) int int4v;

#define KTILES 64                // K/64
#define LDT 72                   // fused-fallback padded row stride

static __device__ __forceinline__ void gload16(const void* g, void* l) {
    __builtin_amdgcn_global_load_lds(
        (const __attribute__((address_space(1))) void*)g,
        (__attribute__((address_space(3))) void*)l, 16, 0, 0);
}

// ---------- Phase 1a: dequant+delta -> fp16, tile-packed + swizzled ----------
__global__ __launch_bounds__(256) void k_pack_w(
    const int* __restrict__ qp, const float* __restrict__ sc,
    const float* __restrict__ zr, const float* __restrict__ dwt,
    unsigned char* __restrict__ Wp)
{
    const long t = (long)blockIdx.x * 256 + threadIdx.x;
    const long flat = t * 8;
    const int g = (int)(flat >> 7);
    const float s = sc[g];
    const float zs = zr[g] * s;
    int4v q4 = *(const int4v*)(qp + (flat >> 1));
    float4v d0 = *(const float4v*)(dwt + flat);
    float4v d1 = *(const float4v*)(dwt + flat + 4);
    float d[8] = {d0[0], d0[1], d0[2], d0[3], d1[0], d1[1], d1[2], d1[3]};
    half8v vh;
#pragma unroll
    for (int j = 0; j < 4; ++j) {
        vh[2*j]   = (half_t)fmaf((float)(q4[j] & 15),        s, d[2*j]   - zs);
        vh[2*j+1] = (half_t)fmaf((float)((q4[j] >> 4) & 15), s, d[2*j+1] - zs);
    }
    const int n = (int)(flat >> 12);
    const int k = (int)(flat & 4095);
    const int row = n & 127;
    const int a = (row << 7) + ((k & 63) << 1);
    const int b = a ^ ((row & 7) << 4);
    *(half8v*)(Wp + (((size_t)((n >> 7) * KTILES + (k >> 6))) << 14) + b) = vh;
}

// ---------- Phase 1b: x fp32 -> fp16, tile-packed + swizzled ----------
__global__ __launch_bounds__(256) void k_pack_x(
    const float* __restrict__ X, unsigned char* __restrict__ Xp)
{
    const long flat = ((long)blockIdx.x * 256 + threadIdx.x) * 8;
    float4v x0 = *(const float4v*)(X + flat);
    float4v x1 = *(const float4v*)(X + flat + 4);
    half8v vh;
    vh[0] = (half_t)x0[0]; vh[1] = (half_t)x0[1];
    vh[2] = (half_t)x0[2]; vh[3] = (half_t)x0[3];
    vh[4] = (half_t)x1[0]; vh[5] = (half_t)x1[1];
    vh[6] = (half_t)x1[2]; vh[7] = (half_t)x1[3];
    const int m = (int)(flat >> 12);
    const int k = (int)(flat & 4095);
    const int row = m & 127;
    const int a = (row << 7) + ((k & 63) << 1);
    const int b = a ^ ((row & 7) << 4);
    *(half8v*)(Xp + (((size_t)((m >> 7) * KTILES + (k >> 6))) << 14) + b) = vh;
}

// ---------- 8-phase 256x256 GEMM ----------
#define BARX() do { __builtin_amdgcn_sched_barrier(0); \
                    __builtin_amdgcn_s_barrier(); \
                    __builtin_amdgcn_sched_barrier(0); } while(0)
#define WAITV(N) do { asm volatile("s_waitcnt vmcnt(" #N ")" ::: "memory"); \
                      __builtin_amdgcn_sched_barrier(0); } while(0)

#define READ_A(BUF, F0) do { \
_Pragma("unroll") for (int i_ = 0; i_ < 4; ++i_) { \
    const int row_ = ((F0) + i_) * 16 + fr; \
_Pragma("unroll") for (int ks_ = 0; ks_ < 2; ++ks_) { \
        const int off_ = ks_ * 64 + kg16; \
        ah[i_][ks_] = *(const half8v*)(&lds[BUF][wm][row_ * 128 + (off_ ^ swz)]); \
    } } } while(0)

#define READ_B(BUF, DST, J0) do { \
_Pragma("unroll") for (int j_ = 0; j_ < 2; ++j_) { \
    const int row_ = bbase + ((J0) + j_) * 16 + fr; \
_Pragma("unroll") for (int ks_ = 0; ks_ < 2; ++ks_) { \
        const int off_ = ks_ * 64 + kg16; \
        DST[j_][ks_] = *(const half8v*)(&lds[BUF][bhalf][row_ * 128 + (off_ ^ swz)]); \
    } } } while(0)

#define MFMA_Q(F0, N0, BREG) do { \
    __builtin_amdgcn_s_setprio(1); \
_Pragma("unroll") for (int i_ = 0; i_ < 4; ++i_) \
_Pragma("unroll") for (int j_ = 0; j_ < 2; ++j_) \
_Pragma("unroll") for (int ks_ = 0; ks_ < 2; ++ks_) \
        acc[(F0)+i_][(N0)+j_] = __builtin_amdgcn_mfma_f32_16x16x32_f16( \
            ah[i_][ks_], BREG[j_][ks_], acc[(F0)+i_][(N0)+j_], 0, 0, 0); \
    __builtin_amdgcn_s_setprio(0); \
} while(0)

__global__ __launch_bounds__(512, 2) void k_gemm8ph(
    const unsigned char* __restrict__ Apk, const unsigned char* __restrict__ Bpk,
    const float* __restrict__ bias, float* __restrict__ Y)
{
    // [buf][half: A0,A1,B0,B1][16KB]
    __shared__ __align__(16) unsigned char lds[2][4][16384];

    const int tid  = threadIdx.x;
    const int lane = tid & 63;
    const int wave = tid >> 6;
    const int wm = wave >> 2;              // 0..1: M half (128 rows)
    const int wn = wave & 3;               // 0..3: N quarter (64 cols)
    const int bhalf = 2 + (wn >> 1);
    const int bbase = (wn & 1) * 64;
    const int fr   = lane & 15;
    const int kg16 = (lane >> 4) << 4;
    const int swz  = (fr & 7) << 4;

    // XCD-aware swizzle: 512 blocks, 8 XCDs, 64 chunks each; N-fastest in chunk
    const int wg = blockIdx.x;
    const int swg = (wg & 7) * 64 + (wg >> 3);
    const int bn = swg & 15;               // N_DIM/256 = 16
    const int bm = swg >> 4;               // M_DIM/256 = 32

    auto asrc = [&](int h, int tk) {
        return Apk + ((((size_t)(2 * bm + h)) * KTILES + tk) << 14);
    };
    auto bsrc = [&](int h, int tk) {
        return Bpk + ((((size_t)(2 * bn + h)) * KTILES + tk) << 14);
    };
    auto stageh = [&](int b, int h, const unsigned char* s) {
        unsigned char* d = &lds[b][h][tid << 4];
        gload16(s + (tid << 4), d);
        gload16(s + 8192 + (tid << 4), d + 8192);
    };

    half8v ah[4][2], b01[2][2], b23[2][2];
    float4v acc[8][4];
    const float4v zero4 = {0.f, 0.f, 0.f, 0.f};
#pragma unroll
    for (int i = 0; i < 8; ++i)
#pragma unroll
        for (int j = 0; j < 4; ++j) acc[i][j] = zero4;

    // ---- prologue: tile0 (all 4 halves) -> buf0; tile1 A-halves -> buf1 ----
    stageh(0, 0, asrc(0, 0)); stageh(0, 1, asrc(1, 0));
    stageh(0, 2, bsrc(0, 0)); stageh(0, 3, bsrc(1, 0));
    stageh(1, 0, asrc(0, 1)); stageh(1, 1, asrc(1, 1));
    WAITV(4);                      // tile0's 8 loads done; tile1-A in flight
    BARX();

    // ---- 31 steady iterations: K-tiles (2i, 2i+1) ----
    for (int it = 0; it < 31; ++it) {
        const int t1 = 2 * it + 1, t2 = 2 * it + 2, t3 = 2 * it + 3;
        // ===== K-tile 2i (buf0) =====
        // phase 0
        READ_A(0, 0); READ_B(0, b01, 0);
        stageh(1, 2, bsrc(0, t1)); stageh(1, 3, bsrc(1, t1));
        BARX();
        MFMA_Q(0, 0, b01);
        BARX();
        // phase 1
        READ_B(0, b23, 2);
        BARX();
        MFMA_Q(0, 2, b23);
        BARX();
        // phase 2
        READ_A(0, 4);
        BARX();
        MFMA_Q(4, 2, b23);
        BARX();
        // phase 3  (A of buf0 dead since phase-2 barrier)
        stageh(0, 0, asrc(0, t2)); stageh(0, 1, asrc(1, t2));
        BARX();
        MFMA_Q(4, 0, b01);
        WAITV(4);                  // tile t1 resident (A:prev p7 / B:p0)
        BARX();
        // ===== K-tile 2i+1 (buf1) =====
        // phase 4  (B of buf0 dead since phase-1 barrier)
        READ_A(1, 0); READ_B(1, b01, 0);
        stageh(0, 2, bsrc(0, t2)); stageh(0, 3, bsrc(1, t2));
        BARX();
        MFMA_Q(0, 0, b01);
        BARX();
        // phase 5
        READ_B(1, b23, 2);
        BARX();
        MFMA_Q(0, 2, b23);
        BARX();
        // phase 6
        READ_A(1, 4);
        BARX();
        MFMA_Q(4, 2, b23);
        BARX();
        // phase 7
        stageh(1, 0, asrc(0, t3)); stageh(1, 1, asrc(1, t3));
        BARX();
        MFMA_Q(4, 0, b01);
        WAITV(4);                  // tile t2 resident (A:p3 / B:p4)
        BARX();
    }

    // ---- tail: K-tiles 62 (buf0), 63 (buf1) ----
    READ_A(0, 0); READ_B(0, b01, 0);
    stageh(1, 2, bsrc(0, 63)); stageh(1, 3, bsrc(1, 63));
    BARX(); MFMA_Q(0, 0, b01); BARX();
    READ_B(0, b23, 2);
    BARX(); MFMA_Q(0, 2, b23); BARX();
    READ_A(0, 4);
    BARX(); MFMA_Q(4, 2, b23); BARX();
    BARX(); MFMA_Q(4, 0, b01);
    WAITV(0);                      // drain: tile 63 fully resident
    BARX();
    READ_A(1, 0); READ_B(1, b01, 0);
    BARX(); MFMA_Q(0, 0, b01); BARX();
    READ_B(1, b23, 2);
    BARX(); MFMA_Q(0, 2, b23); BARX();
    READ_A(1, 4);
    BARX(); MFMA_Q(4, 2, b23); BARX();
    BARX(); MFMA_Q(4, 0, b01); BARX();

    // ---- epilogue ----
    const long m0 = (long)bm * 256 + wm * 128;
    const long n0 = (long)bn * 256 + wn * 64;
#pragma unroll
    for (int mf = 0; mf < 8; ++mf) {
        const long row = m0 + mf * 16 + (lane >> 4) * 4;
#pragma unroll
        for (int nf = 0; nf < 4; ++nf) {
            const long col = n0 + nf * 16 + (lane & 15);
            const float b = bias[col];
#pragma unroll
            for (int r = 0; r < 4; ++r)
                Y[(row + r) * N_DIM + col] = acc[mf][nf][r] + b;
        }
    }
}

// ---------- fallback (no workspace): fused dequant 128x128 GEMM ----------
__global__ __launch_bounds__(256, 2) void k_gemm_fused(
    const float* __restrict__ X, const int* __restrict__ qp,
    const float* __restrict__ sc, const float* __restrict__ zr,
    const float* __restrict__ dwt,
    const float* __restrict__ bias, float* __restrict__ Y)
{
    __shared__ __align__(16) half_t Ah[128 * LDT];
    __shared__ __align__(16) half_t Bh[128 * LDT];

    const int tid  = threadIdx.x;
    const int lane = tid & 63;
    const int wave = tid >> 6;
    const int wm = wave >> 1, wn = wave & 1;
    const int bn = blockIdx.x & 31;
    const int bm = blockIdx.x >> 5;
    const long m0 = (long)bm * 128;
    const long n0 = (long)bn * 128;
    const int fr = lane & 15;
    const int ko = (lane >> 4) * 8;

    const float4v zero4 = {0.f, 0.f, 0.f, 0.f};
    float4v acc[4][4];
#pragma unroll
    for (int i = 0; i < 4; ++i)
#pragma unroll
        for (int j = 0; j < 4; ++j) acc[i][j] = zero4;

    for (int k0 = 0; k0 < K_DIM; k0 += 64) {
        {
            const int ar = tid >> 4;
            const int ac = (tid & 15) * 4;
#pragma unroll
            for (int rr = 0; rr < 8; ++rr) {
                const int row = ar + rr * 16;
                float4v xv = *(const float4v*)(X + (m0 + row) * K_DIM + k0 + ac);
                half4v h;
#pragma unroll
                for (int j = 0; j < 4; ++j) h[j] = (half_t)xv[j];
                *(half4v*)(Ah + row * LDT + ac) = h;
            }
        }
        {
            const int cr = tid >> 3;
            const int cc = (tid & 7) * 8;
#pragma unroll
            for (int rr = 0; rr < 4; ++rr) {
                const int row = cr + rr * 32;
                const long n = n0 + row;
                const int g = (int)(n * 32 + (k0 >> 7));
                const float s = sc[g];
                const float zs = zr[g] * s;
                const long flat = n * K_DIM + k0 + cc;
                int4v q4 = *(const int4v*)(qp + (flat >> 1));
                float4v d0 = *(const float4v*)(dwt + flat);
                float4v d1 = *(const float4v*)(dwt + flat + 4);
                float d[8] = {d0[0], d0[1], d0[2], d0[3], d1[0], d1[1], d1[2], d1[3]};
                half8v vh;
#pragma unroll
                for (int j = 0; j < 4; ++j) {
                    vh[2*j]   = (half_t)fmaf((float)(q4[j] & 15),        s, d[2*j]   - zs);
                    vh[2*j+1] = (half_t)fmaf((float)((q4[j] >> 4) & 15), s, d[2*j+1] - zs);
                }
                *(half8v*)(Bh + row * LDT + cc) = vh;
            }
        }
        __syncthreads();
#pragma unroll
        for (int ks = 0; ks < 2; ++ks) {
            const int kk = ks * 32 + ko;
            half8v a2[4], b2[4];
#pragma unroll
            for (int i = 0; i < 4; ++i) {
                a2[i] = *(const half8v*)(Ah + (wm * 64 + i * 16 + fr) * LDT + kk);
                b2[i] = *(const half8v*)(Bh + (wn * 64 + i * 16 + fr) * LDT + kk);
            }
#pragma unroll
            for (int i = 0; i < 4; ++i)
#pragma unroll
                for (int j = 0; j < 4; ++j)
                    acc[i][j] = __builtin_amdgcn_mfma_f32_16x16x32_f16(
                        a2[i], b2[j], acc[i][j], 0, 0, 0);
        }
        __syncthreads();
    }

#pragma unroll
    for (int i = 0; i < 4; ++i) {
        const long mrow = m0 + wm * 64 + i * 16 + (lane >> 4) * 4;
#pragma unroll
        for (int j = 0; j < 4; ++j) {
            const long col = n0 + wn * 64 + j * 16 + (lane & 15);
            const float b = bias[col];
#pragma unroll
            for (int r = 0; r < 4; ++r)
                Y[(mrow + r) * N_DIM + col] = acc[i][j][r] + b;
        }
    }
}

extern "C" void kernel_launch(void* const* d_in, const int* in_sizes, int n_in,
                              void* d_out, int out_size, void* d_ws, size_t ws_size,
                              hipStream_t stream)
{
    const float* X  = (const float*)d_in[0];
    const int*   qp = (const int*)d_in[1];
    const float* sc = (const float*)d_in[2];
    const float* zr = (const float*)d_in[3];
    const float* dwt = (const float*)d_in[4];
    const float* bs = (const float*)d_in[5];
    float* Y = (float*)d_out;

    const size_t needB = (size_t)N_DIM * K_DIM * 2;
    const size_t needA = (size_t)M_DIM * K_DIM * 2;

    if (ws_size >= needA + needB) {
        unsigned char* Bpk = (unsigned char*)d_ws;
        unsigned char* Apk = Bpk + needB;
        k_pack_w<<<dim3(NUMEL / 8 / 256), dim3(256), 0, stream>>>(qp, sc, zr, dwt, Bpk);
        k_pack_x<<<dim3((M_DIM * (size_t)K_DIM) / 8 / 256), dim3(256), 0, stream>>>(X, Apk);
        k_gemm8ph<<<dim3((M_DIM / 256) * (N_DIM / 256)), dim3(512), 0, stream>>>(Apk, Bpk, bs, Y);
    } else {
        k_gemm_fused<<<dim3((M_DIM / 128) * (N_DIM / 128)), dim3(256), 0, stream>>>(
            X, qp, sc, zr, dwt, bs, Y);
    }
}

// Round 4
// 278.526 us; speedup vs baseline: 2.8993x; 1.0665x over previous
//
#include <hip/hip_runtime.h>

// y[m,o] = sum_k x[m,k] * (W[o,k] + dW[o,k]) + bias[o],  W int4-dequant.
// M=8192, N=4096(OUT), K=4096(IN).
//
// Round 4: 256x256 8-phase GEMM with ONE barrier per phase.
// Phase pattern: [reads_p][stage_p][waitv?][BAR][MFMA_p].
// Safety rule (proved via per-wave lgkmcnt + barrier ordering): a stage in
// phase p may target any LDS region whose last ds_read was in phase <= p-2.
//   reads:  p0: A(buf0)[0-3]+B(buf0)[0-1] | p1: B(buf0)[2-3] | p2: A(buf0)[4-7]
//           p4/p5/p6: same on buf1        | p3,p7: none
//   stages: p0: A(buf1,t+1) gap2 | p3: B(buf0,t+2) gap2
//           p4: A(buf0,t+2) gap2 | p7: B(buf1,t+3) gap2
//   waits:  vmcnt(4) before BAR at p3 (buf1 tile resident) and p7 (buf0).

#define M_DIM 8192
#define N_DIM 4096
#define K_DIM 4096
#define NUMEL (N_DIM * K_DIM)

typedef _Float16 half_t;
typedef __attribute__((ext_vector_type(4))) _Float16 half4v;
typedef __attribute__((ext_vector_type(8))) _Float16 half8v;
typedef __attribute__((ext_vector_type(4))) float float4v;
typedef __attribute__((ext_vector_type(4))) int int4v;

#define KTILES 64
#define LDT 72

static __device__ __forceinline__ void gload16(const void* g, void* l) {
    __builtin_amdgcn_global_load_lds(
        (const __attribute__((address_space(1))) void*)g,
        (__attribute__((address_space(3))) void*)l, 16, 0, 0);
}

// ---------- Phase 1a: dequant+delta -> fp16, tile-packed + swizzled ----------
__global__ __launch_bounds__(256) void k_pack_w(
    const int* __restrict__ qp, const float* __restrict__ sc,
    const float* __restrict__ zr, const float* __restrict__ dwt,
    unsigned char* __restrict__ Wp)
{
    const long t = (long)blockIdx.x * 256 + threadIdx.x;
    const long flat = t * 8;
    const int g = (int)(flat >> 7);
    const float s = sc[g];
    const float zs = zr[g] * s;
    int4v q4 = *(const int4v*)(qp + (flat >> 1));
    float4v d0 = *(const float4v*)(dwt + flat);
    float4v d1 = *(const float4v*)(dwt + flat + 4);
    float d[8] = {d0[0], d0[1], d0[2], d0[3], d1[0], d1[1], d1[2], d1[3]};
    half8v vh;
#pragma unroll
    for (int j = 0; j < 4; ++j) {
        vh[2*j]   = (half_t)fmaf((float)(q4[j] & 15),        s, d[2*j]   - zs);
        vh[2*j+1] = (half_t)fmaf((float)((q4[j] >> 4) & 15), s, d[2*j+1] - zs);
    }
    const int n = (int)(flat >> 12);
    const int k = (int)(flat & 4095);
    const int row = n & 127;
    const int a = (row << 7) + ((k & 63) << 1);
    const int b = a ^ ((row & 7) << 4);
    *(half8v*)(Wp + (((size_t)((n >> 7) * KTILES + (k >> 6))) << 14) + b) = vh;
}

// ---------- Phase 1b: x fp32 -> fp16, tile-packed + swizzled ----------
__global__ __launch_bounds__(256) void k_pack_x(
    const float* __restrict__ X, unsigned char* __restrict__ Xp)
{
    const long flat = ((long)blockIdx.x * 256 + threadIdx.x) * 8;
    float4v x0 = *(const float4v*)(X + flat);
    float4v x1 = *(const float4v*)(X + flat + 4);
    half8v vh;
    vh[0] = (half_t)x0[0]; vh[1] = (half_t)x0[1];
    vh[2] = (half_t)x0[2]; vh[3] = (half_t)x0[3];
    vh[4] = (half_t)x1[0]; vh[5] = (half_t)x1[1];
    vh[6] = (half_t)x1[2]; vh[7] = (half_t)x1[3];
    const int m = (int)(flat >> 12);
    const int k = (int)(flat & 4095);
    const int row = m & 127;
    const int a = (row << 7) + ((k & 63) << 1);
    const int b = a ^ ((row & 7) << 4);
    *(half8v*)(Xp + (((size_t)((m >> 7) * KTILES + (k >> 6))) << 14) + b) = vh;
}

// ---------- 8-phase 256x256 GEMM, 1 barrier/phase ----------
#define BARX() do { __builtin_amdgcn_sched_barrier(0); \
                    __builtin_amdgcn_s_barrier(); \
                    __builtin_amdgcn_sched_barrier(0); } while(0)
#define WAITV(N) do { asm volatile("s_waitcnt vmcnt(" #N ")" ::: "memory"); \
                      __builtin_amdgcn_sched_barrier(0); } while(0)

#define READ_A(BUF, F0) do { \
_Pragma("unroll") for (int i_ = 0; i_ < 4; ++i_) { \
    const int row_ = ((F0) + i_) * 16 + fr; \
_Pragma("unroll") for (int ks_ = 0; ks_ < 2; ++ks_) { \
        const int off_ = ks_ * 64 + kg16; \
        ah[i_][ks_] = *(const half8v*)(&lds[BUF][wm][row_ * 128 + (off_ ^ swz)]); \
    } } } while(0)

#define READ_B(BUF, DST, J0) do { \
_Pragma("unroll") for (int j_ = 0; j_ < 2; ++j_) { \
    const int row_ = bbase + ((J0) + j_) * 16 + fr; \
_Pragma("unroll") for (int ks_ = 0; ks_ < 2; ++ks_) { \
        const int off_ = ks_ * 64 + kg16; \
        DST[j_][ks_] = *(const half8v*)(&lds[BUF][bhalf][row_ * 128 + (off_ ^ swz)]); \
    } } } while(0)

#define MFMA_Q(F0, N0, BREG) do { \
    __builtin_amdgcn_s_setprio(1); \
_Pragma("unroll") for (int i_ = 0; i_ < 4; ++i_) \
_Pragma("unroll") for (int j_ = 0; j_ < 2; ++j_) \
_Pragma("unroll") for (int ks_ = 0; ks_ < 2; ++ks_) \
        acc[(F0)+i_][(N0)+j_] = __builtin_amdgcn_mfma_f32_16x16x32_f16( \
            ah[i_][ks_], BREG[j_][ks_], acc[(F0)+i_][(N0)+j_], 0, 0, 0); \
    __builtin_amdgcn_s_setprio(0); \
} while(0)

__global__ __launch_bounds__(512, 2) void k_gemm8ph(
    const unsigned char* __restrict__ Apk, const unsigned char* __restrict__ Bpk,
    const float* __restrict__ bias, float* __restrict__ Y)
{
    __shared__ __align__(16) unsigned char lds[2][4][16384];  // [buf][A0,A1,B0,B1]

    const int tid  = threadIdx.x;
    const int lane = tid & 63;
    const int wave = tid >> 6;
    const int wm = wave >> 2;
    const int wn = wave & 3;
    const int bhalf = 2 + (wn >> 1);
    const int bbase = (wn & 1) * 64;
    const int fr   = lane & 15;
    const int kg16 = (lane >> 4) << 4;
    const int swz  = (fr & 7) << 4;

    const int wg = blockIdx.x;
    const int swg = (wg & 7) * 64 + (wg >> 3);   // 512 blocks, 8 XCDs, bijective
    const int bn = swg & 15;
    const int bm = swg >> 4;

    auto asrc = [&](int h, int tk) {
        return Apk + ((((size_t)(2 * bm + h)) * KTILES + tk) << 14);
    };
    auto bsrc = [&](int h, int tk) {
        return Bpk + ((((size_t)(2 * bn + h)) * KTILES + tk) << 14);
    };
    auto stageh = [&](int b, int h, const unsigned char* s) {
        unsigned char* d = &lds[b][h][tid << 4];
        gload16(s + (tid << 4), d);
        gload16(s + 8192 + (tid << 4), d + 8192);
    };

    half8v ah[4][2], b01[2][2], b23[2][2];
    float4v acc[8][4];
    const float4v zero4 = {0.f, 0.f, 0.f, 0.f};
#pragma unroll
    for (int i = 0; i < 8; ++i)
#pragma unroll
        for (int j = 0; j < 4; ++j) acc[i][j] = zero4;

    // ---- prologue: tile0 -> buf0 (4 halves); B(tile1) -> buf1 ----
    stageh(0, 0, asrc(0, 0)); stageh(0, 1, asrc(1, 0));
    stageh(0, 2, bsrc(0, 0)); stageh(0, 3, bsrc(1, 0));
    stageh(1, 2, bsrc(0, 1)); stageh(1, 3, bsrc(1, 1));
    WAITV(4);                      // buf0 tile0 resident (per-wave slice)
    BARX();

    for (int it = 0; it < 31; ++it) {
        const int t1 = 2 * it + 1, t2 = 2 * it + 2, t3 = 2 * it + 3;
        // p0: read buf0 A[0-3],B[0-1]; stage A(buf1,t1)
        READ_A(0, 0); READ_B(0, b01, 0);
        stageh(1, 0, asrc(0, t1)); stageh(1, 1, asrc(1, t1));
        BARX();
        MFMA_Q(0, 0, b01);
        // p1: read B[2-3](buf0)
        READ_B(0, b23, 2);
        BARX();
        MFMA_Q(0, 2, b23);
        // p2: read A[4-7](buf0)
        READ_A(0, 4);
        BARX();
        MFMA_Q(4, 2, b23);
        // p3: stage B(buf0,t2); drain for buf1 t1
        stageh(0, 2, bsrc(0, t2)); stageh(0, 3, bsrc(1, t2));
        WAITV(4);
        BARX();
        MFMA_Q(4, 0, b01);
        // p4: read buf1 A[0-3],B[0-1]; stage A(buf0,t2)
        READ_A(1, 0); READ_B(1, b01, 0);
        stageh(0, 0, asrc(0, t2)); stageh(0, 1, asrc(1, t2));
        BARX();
        MFMA_Q(0, 0, b01);
        // p5
        READ_B(1, b23, 2);
        BARX();
        MFMA_Q(0, 2, b23);
        // p6
        READ_A(1, 4);
        BARX();
        MFMA_Q(4, 2, b23);
        // p7: stage B(buf1,t3); drain for buf0 t2
        stageh(1, 2, bsrc(0, t3)); stageh(1, 3, bsrc(1, t3));
        WAITV(4);
        BARX();
        MFMA_Q(4, 0, b01);
    }

    // ---- tail: K-tiles 62 (buf0), 63 (buf1) ----
    READ_A(0, 0); READ_B(0, b01, 0);
    stageh(1, 0, asrc(0, 63)); stageh(1, 1, asrc(1, 63));
    BARX(); MFMA_Q(0, 0, b01);
    READ_B(0, b23, 2);
    BARX(); MFMA_Q(0, 2, b23);
    READ_A(0, 4);
    BARX(); MFMA_Q(4, 2, b23);
    WAITV(0);                      // drain: buf1 tile63 fully staged
    BARX(); MFMA_Q(4, 0, b01);
    READ_A(1, 0); READ_B(1, b01, 0);
    BARX(); MFMA_Q(0, 0, b01);
    READ_B(1, b23, 2);
    BARX(); MFMA_Q(0, 2, b23);
    READ_A(1, 4);
    BARX(); MFMA_Q(4, 2, b23);
    MFMA_Q(4, 0, b01);

    // ---- epilogue ----
    const long m0 = (long)bm * 256 + wm * 128;
    const long n0 = (long)bn * 256 + wn * 64;
#pragma unroll
    for (int mf = 0; mf < 8; ++mf) {
        const long row = m0 + mf * 16 + (lane >> 4) * 4;
#pragma unroll
        for (int nf = 0; nf < 4; ++nf) {
            const long col = n0 + nf * 16 + (lane & 15);
            const float b = bias[col];
#pragma unroll
            for (int r = 0; r < 4; ++r)
                Y[(row + r) * N_DIM + col] = acc[mf][nf][r] + b;
        }
    }
}

// ---------- fallback (no workspace): fused dequant 128x128 GEMM ----------
__global__ __launch_bounds__(256, 2) void k_gemm_fused(
    const float* __restrict__ X, const int* __restrict__ qp,
    const float* __restrict__ sc, const float* __restrict__ zr,
    const float* __restrict__ dwt,
    const float* __restrict__ bias, float* __restrict__ Y)
{
    __shared__ __align__(16) half_t Ah[128 * LDT];
    __shared__ __align__(16) half_t Bh[128 * LDT];

    const int tid  = threadIdx.x;
    const int lane = tid & 63;
    const int wave = tid >> 6;
    const int wm = wave >> 1, wn = wave & 1;
    const int bn = blockIdx.x & 31;
    const int bm = blockIdx.x >> 5;
    const long m0 = (long)bm * 128;
    const long n0 = (long)bn * 128;
    const int fr = lane & 15;
    const int ko = (lane >> 4) * 8;

    const float4v zero4 = {0.f, 0.f, 0.f, 0.f};
    float4v acc[4][4];
#pragma unroll
    for (int i = 0; i < 4; ++i)
#pragma unroll
        for (int j = 0; j < 4; ++j) acc[i][j] = zero4;

    for (int k0 = 0; k0 < K_DIM; k0 += 64) {
        {
            const int ar = tid >> 4;
            const int ac = (tid & 15) * 4;
#pragma unroll
            for (int rr = 0; rr < 8; ++rr) {
                const int row = ar + rr * 16;
                float4v xv = *(const float4v*)(X + (m0 + row) * K_DIM + k0 + ac);
                half4v h;
#pragma unroll
                for (int j = 0; j < 4; ++j) h[j] = (half_t)xv[j];
                *(half4v*)(Ah + row * LDT + ac) = h;
            }
        }
        {
            const int cr = tid >> 3;
            const int cc = (tid & 7) * 8;
#pragma unroll
            for (int rr = 0; rr < 4; ++rr) {
                const int row = cr + rr * 32;
                const long n = n0 + row;
                const int g = (int)(n * 32 + (k0 >> 7));
                const float s = sc[g];
                const float zs = zr[g] * s;
                const long flat = n * K_DIM + k0 + cc;
                int4v q4 = *(const int4v*)(qp + (flat >> 1));
                float4v d0 = *(const float4v*)(dwt + flat);
                float4v d1 = *(const float4v*)(dwt + flat + 4);
                float d[8] = {d0[0], d0[1], d0[2], d0[3], d1[0], d1[1], d1[2], d1[3]};
                half8v vh;
#pragma unroll
                for (int j = 0; j < 4; ++j) {
                    vh[2*j]   = (half_t)fmaf((float)(q4[j] & 15),        s, d[2*j]   - zs);
                    vh[2*j+1] = (half_t)fmaf((float)((q4[j] >> 4) & 15), s, d[2*j+1] - zs);
                }
                *(half8v*)(Bh + row * LDT + cc) = vh;
            }
        }
        __syncthreads();
#pragma unroll
        for (int ks = 0; ks < 2; ++ks) {
            const int kk = ks * 32 + ko;
            half8v a2[4], b2[4];
#pragma unroll
            for (int i = 0; i < 4; ++i) {
                a2[i] = *(const half8v*)(Ah + (wm * 64 + i * 16 + fr) * LDT + kk);
                b2[i] = *(const half8v*)(Bh + (wn * 64 + i * 16 + fr) * LDT + kk);
            }
#pragma unroll
            for (int i = 0; i < 4; ++i)
#pragma unroll
                for (int j = 0; j < 4; ++j)
                    acc[i][j] = __builtin_amdgcn_mfma_f32_16x16x32_f16(
                        a2[i], b2[j], acc[i][j], 0, 0, 0);
        }
        __syncthreads();
    }

#pragma unroll
    for (int i = 0; i < 4; ++i) {
        const long mrow = m0 + wm * 64 + i * 16 + (lane >> 4) * 4;
#pragma unroll
        for (int j = 0; j < 4; ++j) {
            const long col = n0 + wn * 64 + j * 16 + (lane & 15);
            const float b = bias[col];
#pragma unroll
            for (int r = 0; r < 4; ++r)
                Y[(mrow + r) * N_DIM + col] = acc[i][j][r] + b;
        }
    }
}

extern "C" void kernel_launch(void* const* d_in, const int* in_sizes, int n_in,
                              void* d_out, int out_size, void* d_ws, size_t ws_size,
                              hipStream_t stream)
{
    const float* X  = (const float*)d_in[0];
    const int*   qp = (const int*)d_in[1];
    const float* sc = (const float*)d_in[2];
    const float* zr = (const float*)d_in[3];
    const float* dwt = (const float*)d_in[4];
    const float* bs = (const float*)d_in[5];
    float* Y = (float*)d_out;

    const size_t needB = (size_t)N_DIM * K_DIM * 2;
    const size_t needA = (size_t)M_DIM * K_DIM * 2;

    if (ws_size >= needA + needB) {
        unsigned char* Bpk = (unsigned char*)d_ws;
        unsigned char* Apk = Bpk + needB;
        k_pack_w<<<dim3(NUMEL / 8 / 256), dim3(256), 0, stream>>>(qp, sc, zr, dwt, Bpk);
        k_pack_x<<<dim3((M_DIM * (size_t)K_DIM) / 8 / 256), dim3(256), 0, stream>>>(X, Apk);
        k_gemm8ph<<<dim3((M_DIM / 256) * (N_DIM / 256)), dim3(512), 0, stream>>>(Apk, Bpk, bs, Y);
    } else {
        k_gemm_fused<<<dim3((M_DIM / 128) * (N_DIM / 128)), dim3(256), 0, stream>>>(
            X, qp, sc, zr, dwt, bs, Y);
    }
}